// Round 1
// baseline (259.914 us; speedup 1.0000x reference)
//
#include <hip/hip_runtime.h>
#include <hip/hip_bf16.h>
#include <stdint.h>

#define NSTEP   32
#define BATCH   65536
#define NTHR    512
#define RPH     128          /* rows per half = 8 waves x 16 */
#define DELTA_F (1.0f/32.0f)
#define LN2PI_F 1.83787706640934534f

// R20: register-cache all W2 fragments (wave-invariant, re-read 64x/wave from
// LDS before). Removes 32 of 76 ds_read_b128 per step per wave (-42% LDS read
// traffic) on an LDS-pipe-bound kernel. VGPR 100 -> ~230 (budget 256 @ 2 w/EU).
// Everything else identical to R19 champion (barrier-free, software-pipelined,
// setprio around MFMA clusters, persistent blocks, 2 halves).
#define RB      272
#define OFF_W1  0            /* W1^T [128 nu][136] u16 (b1 baked @ k=80) */
#define OFF_W2  34816        /* W2^T [128 nu][136] u16 (staged once, reg-cached) */
#define OFF_W3  69632        /* W3comb [16 m][136] u16 */
#define OFF_W8  73984        /* f32[128]: W1 row 80 (t coefficient) */
#define OFF_B2  74496        /* f32[128]: b2 */
#define OFF_WB  75008        /* 8 waves x [16 r][136] transpose buffers (4352 B each) */
#define LDS_BYTES 109824     /* 1 block/CU */

typedef __attribute__((ext_vector_type(8))) short    s16x8;
typedef __attribute__((ext_vector_type(8))) __bf16   bf16x8;
typedef __attribute__((ext_vector_type(4))) float    f32x4;
typedef __attribute__((ext_vector_type(4))) int      i32x4;
typedef __attribute__((ext_vector_type(4))) unsigned u32x4;
typedef __attribute__((ext_vector_type(2))) unsigned u32x2;

static __device__ __forceinline__ f32x4 mfma16(s16x8 a, s16x8 b, f32x4 c){
    return __builtin_amdgcn_mfma_f32_16x16x32_bf16(
        __builtin_bit_cast(bf16x8, a), __builtin_bit_cast(bf16x8, b), c, 0, 0, 0);
}

static __device__ __forceinline__ unsigned short f2bf(float f){
    union { float f; unsigned u; } v; v.f = f;
    unsigned u = v.u + 0x7fffu + ((v.u >> 16) & 1u);   // RNE
    return (unsigned short)(u >> 16);
}

static __device__ __forceinline__ unsigned cvtpk(float lo, float hi){
    unsigned r;
    asm("v_cvt_pk_bf16_f32 %0, %1, %2" : "=v"(r) : "v"(lo), "v"(hi));
    return r;
}

static __device__ __forceinline__ s16x8 pconv(i32x4 u0, i32x4 u1){
    const unsigned P = 0x3F80u, M = 0xBF80u;
    u32x4 d;
    d[0] = (u0[0] ? P : M) | ((u0[1] ? P : M) << 16);
    d[1] = (u0[2] ? P : M) | ((u0[3] ? P : M) << 16);
    d[2] = (u1[0] ? P : M) | ((u1[1] ? P : M) << 16);
    d[3] = (u1[2] ? P : M) | ((u1[3] ? P : M) << 16);
    return __builtin_bit_cast(s16x8, d);
}

static __device__ __forceinline__ void relu_pack(f32x4 pre, f32x4 tan, u32x2* H, u32x2* T){
    float h0 = pre[0]>0.f?pre[0]:0.f, h1 = pre[1]>0.f?pre[1]:0.f;
    float h2 = pre[2]>0.f?pre[2]:0.f, h3 = pre[3]>0.f?pre[3]:0.f;
    float s0 = pre[0]>0.f?tan[0]:0.f, s1 = pre[1]>0.f?tan[1]:0.f;
    float s2 = pre[2]>0.f?tan[2]:0.f, s3 = pre[3]>0.f?tan[3]:0.f;
    H->x = cvtpk(h0,h1); H->y = cvtpk(h2,h3);
    T->x = cvtpk(s0,s1); T->y = cvtpk(s2,s3);
}

__global__ __launch_bounds__(NTHR, 2)   // 2 waves/EU -> 256-reg unified budget (design needs ~230)
void cfm_kernel(const float* __restrict__ s_g,
                const float* __restrict__ a0_g,
                const int*   __restrict__ rad_g,
                const float* __restrict__ W1g, const float* __restrict__ b1g,
                const float* __restrict__ W2g, const float* __restrict__ b2g,
                const float* __restrict__ W3g, const float* __restrict__ b3g,
                float* __restrict__ out_g)
{
    extern __shared__ char lds[];
    const int tid  = threadIdx.x;
    const int lane = tid & 63;
    const int wv   = tid >> 6;     // 0..7
    const int c    = lane & 15;
    const int g    = lane >> 4;

    unsigned short* W1t = (unsigned short*)(lds + OFF_W1);
    unsigned short* W2t = (unsigned short*)(lds + OFF_W2);
    unsigned short* W3c = (unsigned short*)(lds + OFF_W3);
    float* W8L = (float*)(lds + OFF_W8);
    float* B2L = (float*)(lds + OFF_B2);

    // ---------------- stage shared weights ONCE (only barrier in the kernel) ----------------
    for (int idx = tid; idx < 128*128; idx += NTHR){
        int n = idx >> 7, k = idx & 127;
        if (k < 96)
            W1t[n*136 + k] = f2bf(k < 80 ? W1g[k*128 + n] : (k == 80 ? b1g[n] : 0.0f));
        W2t[n*136 + k] = f2bf(W2g[k*128 + n]);
    }
    for (int idx = tid; idx < 16*128; idx += NTHR){
        int m = idx >> 7, k = idx & 127;
        W3c[m*136 + k] = f2bf(W3g[k*32 + m] + W3g[k*32 + 16 + m]);
    }
    if (tid < 128)       W8L[tid]       = W1g[80*128 + tid];
    else if (tid < 256)  B2L[tid - 128] = b2g[tid - 128];
    __syncthreads();

    // per-lane LDS bases (in-loop = base + compile-time offset)
    const char* pW1  = lds + OFF_W1 + c*RB + g*16;
    const char* pW2  = lds + OFF_W2 + c*RB + g*16;
    const char* pW3  = lds + OFF_W3 + c*RB + g*16;
    char*       pWBw = lds + OFF_WB + wv*4352 + c*RB + g*8;
    const char* pWBr = lds + OFF_WB + wv*4352 + c*RB + g*16;
    const char* pW8  = lds + OFF_W8 + g*16;
    const char* pB2  = lds + OFF_B2 + g*16;

    // ---- register-cache all W2 A-fragments (wave-invariant, reused 64x) ----
    // 32 x s16x8 = 128 VGPRs. Eliminates the 32 ds_read_b128/step that were
    // 42% of the LDS read traffic on an LDS-pipe-bound kernel.
    s16x8 w2r[4][8];
#pragma unroll
    for (int p = 0; p < 4; ++p)
#pragma unroll
        for (int n2 = 0; n2 < 8; ++n2)
            w2r[p][n2] = *(const s16x8*)(pW2 + n2*4352 + p*64);

    f32x4 b3i;
    {
        f32x4 x0 = *(const f32x4*)(b3g + 4*g);
        f32x4 x1 = *(const f32x4*)(b3g + 16 + 4*g);
        b3i = x0 + x1;
    }

    // ---------------- two 128-row halves, weights persistent ----------------
    for (int half = 0; half < 2; ++half){
        const int row = blockIdx.x * (2*RPH) + half*RPH + wv*16 + c;

        // per-lane X fragments: k: a 0..15 | s 16..79 | 1.0 @80 | 0 81..95
        const float* srow = s_g + (size_t)row * 64;
        s16x8 xf0, xf1, xf2;
#pragma unroll
        for (int j = 0; j < 8; ++j) xf1[j] = (short)f2bf(srow[16 + 8*g + j]);
        if (g >= 2){
#pragma unroll
            for (int j = 0; j < 8; ++j) xf0[j] = (short)f2bf(srow[8*(g-2) + j]);
        }
        if (g < 2){
#pragma unroll
            for (int j = 0; j < 8; ++j) xf2[j] = (short)f2bf(srow[48 + 8*g + j]);
        } else {
#pragma unroll
            for (int j = 0; j < 8; ++j) xf2[j] = 0;
            if (g == 2) xf2[0] = (short)0x3F80;   // X[80] = 1.0 (feeds baked b1)
        }

        f32x4 av = *(const f32x4*)(a0_g + (size_t)row*16 + 4*g);
        float ldet = 0.0f;
        {
            unsigned d0 = cvtpk(av[0], av[1]), d1 = cvtpk(av[2], av[3]);
            int sA = (c + 32*g) & 63, sB = (c + 32*g + 16) & 63;
            unsigned w0 = __shfl(d0, sA, 64), w1 = __shfl(d1, sA, 64);
            unsigned w2 = __shfl(d0, sB, 64), w3 = __shfl(d1, sB, 64);
            if (g < 2){ u32x4 tv = {w0, w1, w2, w3}; xf0 = __builtin_bit_cast(s16x8, tv); }
        }

        const int* rpp = rad_g + ((size_t)row << 4) + 8*(g & 1);
        const int* rps = rad_g + ((size_t)row << 4) + 4*g;
        s16x8 pf;
        if (g < 2){
            i32x4 a = *(const i32x4*)rpp;
            i32x4 b = *(const i32x4*)(rpp + 4);
            pf = pconv(a, b);
        } else {
#pragma unroll
            for (int j = 0; j < 8; ++j) pf[j] = 0;
        }
        const int* rppN = rpp + (size_t)BATCH*16;

        for (int t = 0; t < NSTEP; ++t){
            const float tmid = ((float)t + 0.5f) * DELTA_F;

            i32x4 un0 = {0,0,0,0}, un1 = {0,0,0,0};
            if (g < 2 && t + 1 < NSTEP){
                un0 = *(const i32x4*)rppN;
                un1 = *(const i32x4*)(rppN + 4);
            }
            i32x4 us = *(const i32x4*)rps;

            f32x4 F[8], T[8];
#pragma unroll
            for (int n2 = 0; n2 < 8; ++n2){
                F[n2] = *(const f32x4*)(pB2 + n2*64);
                T[n2] = (f32x4){0,0,0,0};
            }

            // L1 chunk compute+pack+write (chunk p -> parity slot p&1)
            auto l1_chunk = [&](int p){
                const int po = (p & 1) << 7;
                s16x8 aA0 = *(const s16x8*)(pW1 + p*8704);
                s16x8 aB0 = *(const s16x8*)(pW1 + p*8704 + 4352);
                f32x4 w8a = *(const f32x4*)(pW8 + (2*p)*64);
                f32x4 w8b = *(const f32x4*)(pW8 + (2*p+1)*64);
                f32x4 hA = { tmid*w8a[0], tmid*w8a[1], tmid*w8a[2], tmid*w8a[3] };
                f32x4 hB = { tmid*w8b[0], tmid*w8b[1], tmid*w8b[2], tmid*w8b[3] };
                hA = mfma16(aA0, xf0, hA);
                hB = mfma16(aB0, xf0, hB);
                s16x8 aA1 = *(const s16x8*)(pW1 + p*8704 + 64);
                s16x8 aB1 = *(const s16x8*)(pW1 + p*8704 + 4352 + 64);
                hA = mfma16(aA1, xf1, hA);
                hB = mfma16(aB1, xf1, hB);
                s16x8 aA2 = *(const s16x8*)(pW1 + p*8704 + 128);
                s16x8 aB2 = *(const s16x8*)(pW1 + p*8704 + 4352 + 128);
                hA = mfma16(aA2, xf2, hA);
                hB = mfma16(aB2, xf2, hB);
                f32x4 z = {0,0,0,0};
                f32x4 tA = mfma16(aA0, pf, z);
                f32x4 tB = mfma16(aB0, pf, z);
                u32x2 HA, TA, HB, TB;
                relu_pack(hA, tA, &HA, &TA);
                relu_pack(hB, tB, &HB, &TB);
                *(u32x2*)(pWBw + po)      = HA;
                *(u32x2*)(pWBw + po + 32) = HB;
                *(u32x2*)(pWBw + po + 64) = TA;
                *(u32x2*)(pWBw + po + 96) = TB;
            };

            // ---- pipelined L1 -> L2: write chunk p+1, read chunk p (settled) ----
            __builtin_amdgcn_s_setprio(1);
            l1_chunk(0);
#pragma unroll
            for (int p = 0; p < 4; ++p){
                if (p < 3) l1_chunk(p + 1);
                const int po = (p & 1) << 7;
                s16x8 bh = *(const s16x8*)(pWBr + po);
                s16x8 bt = *(const s16x8*)(pWBr + po + 64);
#pragma unroll
                for (int n2 = 0; n2 < 8; ++n2){
                    F[n2] = mfma16(w2r[p][n2], bh, F[n2]);
                    T[n2] = mfma16(w2r[p][n2], bt, T[n2]);
                }
            }
            __builtin_amdgcn_s_setprio(0);

            // ---- pipelined L2 epilogue -> L3 (combined W3) ----
            auto l3_pack = [&](int e){
                const int po = (e & 1) << 7;
                u32x2 HA, TA, HB, TB;
                relu_pack(F[2*e],   T[2*e],   &HA, &TA);
                relu_pack(F[2*e+1], T[2*e+1], &HB, &TB);
                *(u32x2*)(pWBw + po)      = HA;
                *(u32x2*)(pWBw + po + 32) = HB;
                *(u32x2*)(pWBw + po + 64) = TA;
                *(u32x2*)(pWBw + po + 96) = TB;
            };
            f32x4 vf = b3i, vt = {0,0,0,0};
            l3_pack(0);
            __builtin_amdgcn_s_setprio(1);
#pragma unroll
            for (int e = 0; e < 4; ++e){
                if (e < 3) l3_pack(e + 1);
                const int po = (e & 1) << 7;
                s16x8 bh = *(const s16x8*)(pWBr + po);
                s16x8 bt = *(const s16x8*)(pWBr + po + 64);
                s16x8 w3 = *(const s16x8*)(pW3 + e*64);
                vf = mfma16(w3, bh, vf);
                vt = mfma16(w3, bt, vt);
            }
            __builtin_amdgcn_s_setprio(0);

            // ---- Euler update + X a-part refresh ----
            av[0] += DELTA_F * vf[0];
            av[1] += DELTA_F * vf[1];
            av[2] += DELTA_F * vf[2];
            av[3] += DELTA_F * vf[3];
            {
                unsigned d0 = cvtpk(av[0], av[1]), d1 = cvtpk(av[2], av[3]);
                int sA = (c + 32*g) & 63, sB = (c + 32*g + 16) & 63;
                unsigned w0 = __shfl(d0, sA, 64), w1 = __shfl(d1, sA, 64);
                unsigned w2 = __shfl(d0, sB, 64), w3 = __shfl(d1, sB, 64);
                if (g < 2){ u32x4 tv = {w0, w1, w2, w3}; xf0 = __builtin_bit_cast(s16x8, tv); }
            }

            // ---- Hutchinson div ----
            {
                int s0 = us[0] ? 0 : (int)0x80000000u;
                int s1 = us[1] ? 0 : (int)0x80000000u;
                int s2 = us[2] ? 0 : (int)0x80000000u;
                int s3 = us[3] ? 0 : (int)0x80000000u;
                float q0 = __int_as_float(__float_as_int(vt[0]) ^ s0);
                float q1 = __int_as_float(__float_as_int(vt[1]) ^ s1);
                float q2 = __int_as_float(__float_as_int(vt[2]) ^ s2);
                float q3 = __int_as_float(__float_as_int(vt[3]) ^ s3);
                float prod = (q0 + q1) + (q2 + q3);
                prod += __shfl_xor(prod, 16, 64);
                prod += __shfl_xor(prod, 32, 64);
                ldet -= DELTA_F * prod;
            }

            if (g < 2 && t + 1 < NSTEP) pf = pconv(un0, un1);
            rppN += (size_t)BATCH*16;
            rps  += (size_t)BATCH*16;
        }

        // ---- finalize this half (per-wave, no LDS, no barrier) ----
        float asq = av[0]*av[0] + av[1]*av[1] + av[2]*av[2] + av[3]*av[3];
        asq += __shfl_xor(asq, 16, 64);
        asq += __shfl_xor(asq, 32, 64);
        if (g == 0)
            out_g[row] = -0.5f*asq - 8.0f*LN2PI_F + ldet;
    }
}

extern "C" void kernel_launch(void* const* d_in, const int* in_sizes, int n_in,
                              void* d_out, int out_size, void* d_ws, size_t ws_size,
                              hipStream_t stream)
{
    const float* s_g  = (const float*)d_in[0];
    const float* a0_g = (const float*)d_in[1];
    const int*   rad  = (const int*)  d_in[2];
    const float* W1   = (const float*)d_in[3];
    const float* b1   = (const float*)d_in[4];
    const float* W2   = (const float*)d_in[5];
    const float* b2   = (const float*)d_in[6];
    const float* W3   = (const float*)d_in[7];
    const float* b3   = (const float*)d_in[8];
    float* out = (float*)d_out;

    // opt-in to >64KB dynamic LDS (host-side attribute; capture-safe)
    hipFuncSetAttribute(reinterpret_cast<const void*>(cfm_kernel),
                        hipFuncAttributeMaxDynamicSharedMemorySize, LDS_BYTES);

    cfm_kernel<<<BATCH/(2*RPH), NTHR, LDS_BYTES, stream>>>(
        s_g, a0_g, rad, W1, b1, W2, b2, W3, b3, out);
}